// Round 3
// baseline (49.192 us; speedup 1.0000x reference)
//
#include <hip/hip_runtime.h>

#define NUM_C  16
#define NUM_D  8
#define RECEPT 512
#define NWIN   128
#define LROW   32768
#define EPS_V  1e-4f

// x LDS region: 32768 + 256 (wrap replica) bf16 elements = 66048 bytes
#define XBYTES  66048
#define WQBYTES 32768                      // one W quarter (128 K-cols)
#define LDS_TOTAL (XBYTES + 2 * WQBYTES)   // 131584

typedef __attribute__((ext_vector_type(8))) short short8;
typedef __attribute__((ext_vector_type(4))) float f32x4;

__device__ __forceinline__ unsigned short f2bf(float f) {
    unsigned int u = __builtin_bit_cast(unsigned int, f);
    u += 0x7fffu + ((u >> 16) & 1u);   // round-to-nearest-even
    return (unsigned short)(u >> 16);
}

// XOR swizzle on byte address within the 1-D x LDS buffer (involution applied
// on both staging writes and A-fragment reads; breaks the 512B row stride).
__device__ __forceinline__ int xsw(int a) { return a ^ (((a >> 9) & 7) << 4); }

// ---------------------------------------------------------------------------
// Prep (16 blocks x 256 thr): per c: G = W W^T + eps I ; chol; Wt = L^{-1} W ;
// store Wt bf16 in MFMA B-fragment order:
//   wfrag[ntile(8)][kk(16)][lane(64)][j(8)]
//   value = Wt[cd = ntile*16 + (lane&15)][r = kk*32 + (lane>>4)*8 + j]
// Also zeroes d_out.
// ---------------------------------------------------------------------------
__global__ void prep_kernel(const float* __restrict__ weight,
                            unsigned short* __restrict__ wfrag,
                            float* __restrict__ out) {
    __shared__ float Wc[NUM_D * RECEPT];
    __shared__ float G[NUM_D][NUM_D];
    __shared__ float Lm[NUM_D][NUM_D];
    const int c = blockIdx.x;
    const int t = threadIdx.x;  // 256 threads

    // zero d_out: 8192 floats over 16 blocks x 256 threads = 2 per thread
    out[c * 256 + t] = 0.f;
    out[c * 256 + t + 4096] = 0.f;

    const float4* wsrc4 = reinterpret_cast<const float4*>(
        weight + (size_t)c * NUM_D * RECEPT);
    float4* Wc4 = reinterpret_cast<float4*>(Wc);
    #pragma unroll
    for (int i = 0; i < 4; ++i) Wc4[t + i * 256] = wsrc4[t + i * 256];
    __syncthreads();

    if (t < 64) {
        int d = t >> 3, e = t & 7;
        const float4* wd4 = reinterpret_cast<const float4*>(&Wc[d * RECEPT]);
        const float4* we4 = reinterpret_cast<const float4*>(&Wc[e * RECEPT]);
        float s = 0.f;
        #pragma unroll 4
        for (int r4 = 0; r4 < RECEPT / 4; ++r4) {
            float4 a = wd4[r4], bb = we4[r4];
            s += a.x * bb.x + a.y * bb.y + a.z * bb.z + a.w * bb.w;
        }
        if (d == e) s += EPS_V;
        G[d][e] = s;
    }
    __syncthreads();
    if (t == 0) {
        for (int i = 0; i < NUM_D; ++i) {
            float diag = G[i][i];
            for (int k = 0; k < i; ++k) diag -= Lm[i][k] * Lm[i][k];
            float di = sqrtf(diag);
            Lm[i][i] = di;
            float inv = 1.f / di;
            for (int jj = i + 1; jj < NUM_D; ++jj) {
                float s = G[jj][i];
                for (int k = 0; k < i; ++k) s -= Lm[jj][k] * Lm[i][k];
                Lm[jj][i] = s * inv;
            }
        }
    }
    __syncthreads();
    for (int r = t; r < RECEPT; r += 256) {
        float y[NUM_D];
        for (int d = 0; d < NUM_D; ++d) {
            float s = Wc[d * RECEPT + r];
            for (int k = 0; k < d; ++k) s -= Lm[d][k] * y[k];
            y[d] = s / Lm[d][d];
        }
        const int kk = r >> 5;          // 0..15
        const int g  = (r >> 3) & 3;    // k-group within 32
        const int j  = r & 7;
        for (int d = 0; d < NUM_D; ++d) {
            int cd = c * NUM_D + d;
            int ntile = cd >> 4;
            int nl = cd & 15;
            int lane = g * 16 + nl;
            int idx = (((ntile * 16 + kk) * 64) + lane) * 8 + j;
            wfrag[idx] = f2bf(y[d]);
        }
    }
}

// ---------------------------------------------------------------------------
// Main: one block per b. 512 threads = 8 waves (2 M-groups x 4 N-groups).
// x row staged bf16+swizzled in LDS; W staged in 4 double-buffered 32KB
// quarter-passes with register prefetch overlapping the MFMA compute.
// ---------------------------------------------------------------------------
__global__ __launch_bounds__(512, 2) void main_kernel(
        const float* __restrict__ x,
        const unsigned short* __restrict__ wfrag,
        float* __restrict__ out) {
    extern __shared__ char lds[];
    const int b = blockIdx.x;
    const int t = threadIdx.x;
    const int lane = t & 63;
    const int wv = t >> 6;
    const int wmb = (wv & 1) * 64;    // window (M) base for this wave
    const int wnb = (wv >> 1) * 32;   // cd (N) base for this wave
    const int nt0 = wnb >> 4;
    const int rl = lane & 15;
    const int gl = lane >> 4;

    const float4* xrow4 = reinterpret_cast<const float4*>(x + (size_t)b * LROW);
    const float4* wsrc = reinterpret_cast<const float4*>(wfrag);

    // prefetch W quarter 0 into registers
    // quarter-q LDS layout (f4 idx d): [ntile(8)][kkq(4)][lane f4(64)]
    // src f4 idx = (d>>8)*1024 + q*256 + (d&255)
    float4 wreg[4];
    #pragma unroll
    for (int i = 0; i < 4; ++i) {
        int d = i * 512 + t;
        wreg[i] = wsrc[((d >> 8) << 10) + (d & 255)];
    }

    // stage x row -> bf16 LDS (swizzled), coalesced float4 loads
    #pragma unroll
    for (int i = 0; i < 16; ++i) {
        int f4 = i * 512 + t;                 // float4 chunk index 0..8191
        float4 v = xrow4[f4];
        ushort4 h;
        h.x = f2bf(v.x); h.y = f2bf(v.y); h.z = f2bf(v.z); h.w = f2bf(v.w);
        *reinterpret_cast<ushort4*>(lds + xsw(f4 * 8)) = h;
    }
    if (t < 64) {                             // wrap replica: x[b][0:256]
        float4 v = xrow4[t];
        ushort4 h;
        h.x = f2bf(v.x); h.y = f2bf(v.y); h.z = f2bf(v.z); h.w = f2bf(v.w);
        *reinterpret_cast<ushort4*>(lds + xsw(65536 + t * 8)) = h;
    }
    // write W quarter 0
    {
        float4* wd = reinterpret_cast<float4*>(lds + XBYTES);
        #pragma unroll
        for (int i = 0; i < 4; ++i) wd[i * 512 + t] = wreg[i];
    }
    __syncthreads();

    f32x4 acc[4][2];
    #pragma unroll
    for (int mi = 0; mi < 4; ++mi)
        #pragma unroll
        for (int ni = 0; ni < 2; ++ni)
            acc[mi][ni] = (f32x4){0.f, 0.f, 0.f, 0.f};

    #pragma unroll
    for (int q = 0; q < 4; ++q) {
        // prefetch next quarter into registers (overlaps compute below)
        if (q < 3) {
            #pragma unroll
            for (int i = 0; i < 4; ++i) {
                int d = i * 512 + t;
                wreg[i] = wsrc[((d >> 8) << 10) + (q + 1) * 256 + (d & 255)];
            }
        }
        const char* wb = lds + XBYTES + (q & 1) * WQBYTES;
        #pragma unroll
        for (int kkq = 0; kkq < 4; ++kkq) {
            const int kk = q * 4 + kkq;
            short8 af[4], bf0, bf1;
            const int kb = kk * 64 + gl * 16;
            #pragma unroll
            for (int mi = 0; mi < 4; ++mi) {
                int w = wmb + mi * 16 + rl;
                af[mi] = *reinterpret_cast<const short8*>(lds + xsw(w * 512 + kb));
            }
            bf0 = *reinterpret_cast<const short8*>(wb + ((nt0 * 4 + kkq) * 64 + lane) * 16);
            bf1 = *reinterpret_cast<const short8*>(wb + (((nt0 + 1) * 4 + kkq) * 64 + lane) * 16);
            #pragma unroll
            for (int mi = 0; mi < 4; ++mi) {
                acc[mi][0] = __builtin_amdgcn_mfma_f32_16x16x32_bf16(af[mi], bf0, acc[mi][0], 0, 0, 0);
                acc[mi][1] = __builtin_amdgcn_mfma_f32_16x16x32_bf16(af[mi], bf1, acc[mi][1], 0, 0, 0);
            }
        }
        // write prefetched quarter into the other buffer
        if (q < 3) {
            float4* wd = reinterpret_cast<float4*>(lds + XBYTES + ((q + 1) & 1) * WQBYTES);
            #pragma unroll
            for (int i = 0; i < 4; ++i) wd[i * 512 + t] = wreg[i];
        }
        __syncthreads();
    }

    // epilogue: q = sum over the 8 d-columns of P^2 (lanes differing in bits
    // 0..2), sqrt, then sum over this wave's 64 windows; atomics into out.
    #pragma unroll
    for (int ni = 0; ni < 2; ++ni) {
        float s = 0.f;
        #pragma unroll
        for (int mi = 0; mi < 4; ++mi) {
            #pragma unroll
            for (int r = 0; r < 4; ++r) {
                float p = acc[mi][ni][r];
                float qq = p * p;
                qq += __shfl_xor(qq, 1);
                qq += __shfl_xor(qq, 2);
                qq += __shfl_xor(qq, 4);
                s += sqrtf(qq);
            }
        }
        s += __shfl_xor(s, 16);
        s += __shfl_xor(s, 32);
        if (lane < 16 && (lane & 7) == 0) {
            int c = (wnb + ni * 16 + lane) >> 3;
            atomicAdd(&out[b * NUM_C + c], s * (1.0f / 128.0f));
        }
    }
}

extern "C" void kernel_launch(void* const* d_in, const int* in_sizes, int n_in,
                              void* d_out, int out_size, void* d_ws, size_t ws_size,
                              hipStream_t stream) {
    (void)in_sizes; (void)n_in; (void)ws_size; (void)out_size;
    const float* x      = (const float*)d_in[0];
    const float* weight = (const float*)d_in[1];
    float* out = (float*)d_out;
    unsigned short* wfrag = (unsigned short*)d_ws;   // needs 128 KiB scratch

    prep_kernel<<<16, 256, 0, stream>>>(weight, wfrag, out);

    hipFuncSetAttribute(reinterpret_cast<const void*>(main_kernel),
                        hipFuncAttributeMaxDynamicSharedMemorySize, LDS_TOTAL);
    main_kernel<<<512, 512, LDS_TOTAL, stream>>>(x, wfrag, out);
}

// Round 4
// 34.304 us; speedup vs baseline: 1.4340x; 1.4340x over previous
//
#include <hip/hip_runtime.h>

#define NUM_C  16
#define NUM_D  8
#define RECEPT 512
#define LROW   32768
#define EPS_V  1e-4f

// per-block x slice: 64 windows * 256 stride + 256 overlap = 16640 bf16 elems
#define XELEMS 16640
#define XBYTES 33536   // 33280 rounded up for swizzle headroom (xsw adds <=112)

typedef __attribute__((ext_vector_type(8))) short short8;
typedef __attribute__((ext_vector_type(4))) float f32x4;

__device__ __forceinline__ unsigned short f2bf(float f) {
    unsigned int u = __builtin_bit_cast(unsigned int, f);
    u += 0x7fffu + ((u >> 16) & 1u);   // round-to-nearest-even
    return (unsigned short)(u >> 16);
}

// XOR swizzle on byte address in the 1-D x LDS slice (involution; applied on
// both staging writes and A-fragment reads; breaks the 512B window stride).
__device__ __forceinline__ int xsw(int a) { return a ^ (((a >> 9) & 7) << 4); }

// ---------------------------------------------------------------------------
// Prep (16 blocks x 256 thr): per c: G = W W^T + eps I ; chol; Wt = L^{-1} W ;
// store Wt bf16 in MFMA B-fragment order:
//   wfrag[ntile(8)][kk(16)][lane(64)][j(8)]
//   value = Wt[cd = ntile*16 + (lane&15)][r = kk*32 + (lane>>4)*8 + j]
// Also zeroes d_out.
// ---------------------------------------------------------------------------
__global__ void prep_kernel(const float* __restrict__ weight,
                            unsigned short* __restrict__ wfrag,
                            float* __restrict__ out) {
    __shared__ float Wc[NUM_D * RECEPT];
    __shared__ float G[NUM_D][NUM_D];
    __shared__ float Lm[NUM_D][NUM_D];
    const int c = blockIdx.x;
    const int t = threadIdx.x;  // 256 threads

    // zero d_out: 8192 floats over 16 blocks x 256 threads
    out[c * 256 + t] = 0.f;
    out[c * 256 + t + 4096] = 0.f;

    const float4* wsrc4 = reinterpret_cast<const float4*>(
        weight + (size_t)c * NUM_D * RECEPT);
    float4* Wc4 = reinterpret_cast<float4*>(Wc);
    #pragma unroll
    for (int i = 0; i < 4; ++i) Wc4[t + i * 256] = wsrc4[t + i * 256];
    __syncthreads();

    if (t < 64) {
        int d = t >> 3, e = t & 7;
        const float4* wd4 = reinterpret_cast<const float4*>(&Wc[d * RECEPT]);
        const float4* we4 = reinterpret_cast<const float4*>(&Wc[e * RECEPT]);
        float s = 0.f;
        #pragma unroll 4
        for (int r4 = 0; r4 < RECEPT / 4; ++r4) {
            float4 a = wd4[r4], bb = we4[r4];
            s += a.x * bb.x + a.y * bb.y + a.z * bb.z + a.w * bb.w;
        }
        if (d == e) s += EPS_V;
        G[d][e] = s;
    }
    __syncthreads();
    if (t == 0) {
        for (int i = 0; i < NUM_D; ++i) {
            float diag = G[i][i];
            for (int k = 0; k < i; ++k) diag -= Lm[i][k] * Lm[i][k];
            float di = sqrtf(diag);
            Lm[i][i] = di;
            float inv = 1.f / di;
            for (int jj = i + 1; jj < NUM_D; ++jj) {
                float s = G[jj][i];
                for (int k = 0; k < i; ++k) s -= Lm[jj][k] * Lm[i][k];
                Lm[jj][i] = s * inv;
            }
        }
    }
    __syncthreads();
    for (int r = t; r < RECEPT; r += 256) {
        float y[NUM_D];
        for (int d = 0; d < NUM_D; ++d) {
            float s = Wc[d * RECEPT + r];
            for (int k = 0; k < d; ++k) s -= Lm[d][k] * y[k];
            y[d] = s / Lm[d][d];
        }
        const int kk = r >> 5;          // 0..15
        const int g  = (r >> 3) & 3;    // k-group within 32
        const int j  = r & 7;
        for (int d = 0; d < NUM_D; ++d) {
            int cd = c * NUM_D + d;
            int ntile = cd >> 4;
            int nl = cd & 15;
            int lane = g * 16 + nl;
            int idx = (((ntile * 16 + kk) * 64) + lane) * 8 + j;
            wfrag[idx] = f2bf(y[d]);
        }
    }
}

// ---------------------------------------------------------------------------
// Main: 1024 blocks (b = bid>>1, half h = bid&1) x 256 thr (4 waves).
// Block tile: 64 windows x 128 cd, K=512. x-slice (33.5 KB) staged bf16 in
// LDS -> 4 blocks/CU co-resident. Each wave: 64 win x 32 cd (mi=4, ni=2);
// B fragments streamed global->regs in K-quarters (coalesced, L2-resident).
// ---------------------------------------------------------------------------
__global__ __launch_bounds__(256, 4) void main_kernel(
        const float* __restrict__ x,
        const unsigned short* __restrict__ wfrag,
        float* __restrict__ out) {
    __shared__ char lds[XBYTES];
    const int bid = blockIdx.x;
    const int b = bid >> 1;
    const int h = bid & 1;
    const int t = threadIdx.x;
    const int lane = t & 63;
    const int wv = t >> 6;          // 0..3
    const int rl = lane & 15;
    const int gl = lane >> 4;
    const int nt0 = wv * 2;         // this wave's first ntile

    const float4* s4   = reinterpret_cast<const float4*>(x + (size_t)b * LROW + h * 16384);
    const float4* row4 = reinterpret_cast<const float4*>(x + (size_t)b * LROW);

    // stage x slice -> bf16 LDS (swizzled); 16 coalesced float4 loads/thread
    #pragma unroll
    for (int i = 0; i < 16; ++i) {
        int f4 = i * 256 + t;                 // float4 chunk 0..4095
        float4 v = s4[f4];
        ushort4 hh;
        hh.x = f2bf(v.x); hh.y = f2bf(v.y); hh.z = f2bf(v.z); hh.w = f2bf(v.w);
        *reinterpret_cast<ushort4*>(lds + xsw(f4 * 8)) = hh;
    }
    if (t < 64) {                             // 256-elem overlap tail (wraps at h=1)
        float4 v = h ? row4[t] : s4[4096 + t];
        ushort4 hh;
        hh.x = f2bf(v.x); hh.y = f2bf(v.y); hh.z = f2bf(v.z); hh.w = f2bf(v.w);
        *reinterpret_cast<ushort4*>(lds + xsw((4096 + t) * 8)) = hh;
    }
    __syncthreads();

    f32x4 acc[4][2];
    #pragma unroll
    for (int mi = 0; mi < 4; ++mi)
        #pragma unroll
        for (int ni = 0; ni < 2; ++ni)
            acc[mi][ni] = (f32x4){0.f, 0.f, 0.f, 0.f};

    for (int q = 0; q < 4; ++q) {
        // load this K-quarter's B fragments: 8 coalesced b128 from L2
        short8 bq[4][2];
        #pragma unroll
        for (int kkq = 0; kkq < 4; ++kkq)
            #pragma unroll
            for (int ni = 0; ni < 2; ++ni)
                bq[kkq][ni] = *reinterpret_cast<const short8*>(
                    wfrag + ((size_t)(((nt0 + ni) * 16 + q * 4 + kkq) * 64 + lane)) * 8);

        #pragma unroll
        for (int kkq = 0; kkq < 4; ++kkq) {
            const int kb = (q * 4 + kkq) * 64 + gl * 16;   // byte offset along k
            short8 af[4];
            #pragma unroll
            for (int mi = 0; mi < 4; ++mi)
                af[mi] = *reinterpret_cast<const short8*>(
                    lds + xsw((mi * 16 + rl) * 512 + kb));
            #pragma unroll
            for (int mi = 0; mi < 4; ++mi) {
                acc[mi][0] = __builtin_amdgcn_mfma_f32_16x16x32_bf16(af[mi], bq[kkq][0], acc[mi][0], 0, 0, 0);
                acc[mi][1] = __builtin_amdgcn_mfma_f32_16x16x32_bf16(af[mi], bq[kkq][1], acc[mi][1], 0, 0, 0);
            }
        }
    }

    // epilogue: q = sum over the 8 d-columns of P^2 (lanes differing in bits
    // 0..2), sqrt, sum over this block's 64 windows, atomics into out.
    #pragma unroll
    for (int ni = 0; ni < 2; ++ni) {
        float s = 0.f;
        #pragma unroll
        for (int mi = 0; mi < 4; ++mi) {
            #pragma unroll
            for (int r = 0; r < 4; ++r) {
                float p = acc[mi][ni][r];
                float qq = p * p;
                qq += __shfl_xor(qq, 1);
                qq += __shfl_xor(qq, 2);
                qq += __shfl_xor(qq, 4);
                s += sqrtf(qq);
            }
        }
        s += __shfl_xor(s, 16);
        s += __shfl_xor(s, 32);
        if (lane < 16 && (lane & 7) == 0) {
            int c = (wv * 32 + ni * 16 + lane) >> 3;
            atomicAdd(&out[b * NUM_C + c], s * (1.0f / 128.0f));
        }
    }
}

extern "C" void kernel_launch(void* const* d_in, const int* in_sizes, int n_in,
                              void* d_out, int out_size, void* d_ws, size_t ws_size,
                              hipStream_t stream) {
    (void)in_sizes; (void)n_in; (void)ws_size; (void)out_size;
    const float* x      = (const float*)d_in[0];
    const float* weight = (const float*)d_in[1];
    float* out = (float*)d_out;
    unsigned short* wfrag = (unsigned short*)d_ws;   // needs 128 KiB scratch

    prep_kernel<<<16, 256, 0, stream>>>(weight, wfrag, out);
    main_kernel<<<1024, 256, 0, stream>>>(x, wfrag, out);
}